// Round 7
// baseline (134.757 us; speedup 1.0000x reference)
//
#include <hip/hip_runtime.h>
#include <hip/hip_cooperative_groups.h>

// RegionProposal: decode 55296 anchors -> stable top-6000 by score -> greedy
// NMS (IoU>0.7) -> first 300 kept boxes zero-padded to [300,4] fp32.
//
// Round-7: ONE cooperative kernel (54 blocks x 1024). Evidence from rounds
// 1/2/4/6: this harness charges ~5-14us per extra graph dispatch, so the
// 4-kernel split (round 6, 87us) lost to the 2-kernel round 2 (66.8us).
// Phases, separated by grid.sync():
//   P0: zero hist/cnt; compute fs = flip32(class-1 logit) into registers.
//   P1: global atomicAdd 16384-bin histogram of fs>>18.
//   P2: per-block redundant hist scan -> B1 (rank-512 bin) / B2 (rank-6000
//       bin); wave-aggregated global append: bin<=B1 -> candS, else candL.
//   P3: block 0 only: bitonic sort 1024 S-slots, decode boxes, 384x384
//       lower-tri suppression bitmask, ballot-greedy resolution, chunked NMS
//       remainder, early exit at 300 kept. Fallback (pathological ties /
//       S overflow): full 8192 bitonic over S+L with on-the-fly decode.
//
// Key = (flip32(logit)<<32) | anchor_idx: ascending u64 == descending logit,
// ties by ascending index == stable argsort(-sigmoid(logit)). IoU compare:
// fma-margin test with exact-division fallback inside the +-1e-6 tie-zone ->
// decisions bit-identical to the np reference (absmax 0.0, rounds 1-6).

#define ADIM 9
#define NANCH 55296
#define HWSZ 6144
#define TOPK 6000
#define OUTK 300
#define NBINS 16384
#define CAP 8192
#define SCAP 1024
#define LCAP 7168       // CAP - SCAP
#define RANK1 512
#define MROWS 384
#define MW 6            // MROWS/64
#define THR 0.7f
#define NBLK 54

typedef unsigned long long u64;
typedef unsigned int u32;

__device__ __forceinline__ u32 flipu(u32 b) {
    u32 u = (b & 0x80000000u) ? ~b : (b | 0x80000000u);
    return ~u;                       // ascending result == descending float
}

__device__ __forceinline__ bool iou_gt(float4 a, float aa, float4 b, float ba) {
    float ix = fminf(a.z, b.z) - fmaxf(a.x, b.x);
    float iy = fminf(a.w, b.w) - fmaxf(a.y, b.y);
    float inter = fmaxf(ix, 0.f) * fmaxf(iy, 0.f);
    float u = fmaxf(aa + ba - inter, 1e-12f);
    float d = __builtin_fmaf(-THR, u, inter);           // inter - 0.7*u, 1 rounding
    if (__builtin_fabsf(d) > 1e-6f * u) return d > 0.f; // sign-safe outside tie-zone
    return inter / u > THR;                             // exact IEEE div == np
}

__device__ __forceinline__ float4 decode_box(const float* __restrict__ loc,
                                             const float* __restrict__ anc, u32 n) {
    u32 a = n % ADIM, hw = n / ADIM;
    float t0 = loc[(4 * a + 0) * HWSZ + hw];
    float t1 = loc[(4 * a + 1) * HWSZ + hw];
    float t2 = loc[(4 * a + 2) * HWSZ + hw];
    float t3 = loc[(4 * a + 3) * HWSZ + hw];
    float4 an = reinterpret_cast<const float4*>(anc)[n];
    float cx = t0 * an.z + an.x;
    float cy = t1 * an.w + an.y;
    float bw = expf(t2) * an.z;
    float bh = expf(t3) * an.w;
    return make_float4(fminf(fmaxf(cx - bw * 0.5f, 0.f), 1.f),
                       fminf(fmaxf(cy - bh * 0.5f, 0.f), 1.f),
                       fminf(fmaxf(cx + bw * 0.5f, 0.f), 1.f),
                       fminf(fmaxf(cy + bh * 0.5f, 0.f), 1.f));
}

__device__ __forceinline__ u64 sx64(u64 v, int m) {
    u32 lo = __shfl_xor((u32)(v & 0xffffffffu), m, 64);
    u32 hi = __shfl_xor((u32)(v >> 32), m, 64);
    return ((u64)hi << 32) | lo;
}

__device__ __forceinline__ u64 ce64(u64 v, int j, int lane, bool up) {
    u64 pv = sx64(v, j);
    u64 mn = (pv < v) ? pv : v;
    u64 mx = (pv < v) ? v : pv;
    return (((lane & j) == 0) == up) ? mn : mx;
}

__global__ void __launch_bounds__(1024) k_all(const float* __restrict__ cls,
                                              const float* __restrict__ loc,
                                              const float* __restrict__ anc,
                                              u32* __restrict__ hist,
                                              u32* __restrict__ cnt,
                                              u64* __restrict__ candS,
                                              u64* __restrict__ candL,
                                              float4* __restrict__ out) {
    __shared__ u64 cand[CAP];          // 64 KB
    __shared__ float4 sbox[SCAP];      // 16 KB
    __shared__ float  sarea[SCAP];     // 4 KB
    __shared__ u64 smask[MROWS][MW];   // 18 KB
    __shared__ float4 kept[OUTK];
    __shared__ float  karea[OUTK];
    __shared__ float4 cbox[64];
    __shared__ float  carea[64];
    __shared__ u64 supw[16];
    __shared__ u64 sbyp[1024];         // 8 KB
    __shared__ u32 wsum[16];
    __shared__ u32 sB[2];
    __shared__ u32 shu[8];             // 4:kc 5:i0

    const int tid = threadIdx.x;
    const int wid = tid >> 6;
    const int lane = tid & 63;
    const int bid = blockIdx.x;
    const int g = bid * 1024 + tid;    // [0, 55296)

    cooperative_groups::grid_group grid = cooperative_groups::this_grid();

    // ---- P0: zero hist/cnt; compute my fs ----
    const int ch = g / HWSZ, e = g - ch * HWSZ;
    const u32 fs = flipu(__float_as_uint(cls[(2 * ch + 1) * HWSZ + e]));
    const u64 key = ((u64)fs << 32) | (u32)(e * ADIM + ch);
    if (g < NBINS) hist[g] = 0u;
    if (g < 2) cnt[g] = 0u;
    grid.sync();

    // ---- P1: global histogram ----
    atomicAdd(&hist[fs >> 18], 1u);
    __threadfence();
    grid.sync();

    // ---- P2: per-block redundant scan -> B1/B2; wave-aggregated append ----
    {
        u32 h[16];
        const uint4* h4 = reinterpret_cast<const uint4*>(hist);
        #pragma unroll
        for (int k = 0; k < 4; ++k) {
            uint4 v = h4[tid * 4 + k];
            h[4 * k + 0] = v.x; h[4 * k + 1] = v.y; h[4 * k + 2] = v.z; h[4 * k + 3] = v.w;
        }
        u32 s = 0;
        #pragma unroll
        for (int b = 0; b < 16; ++b) s += h[b];
        u32 x = s;
        #pragma unroll
        for (int d = 1; d < 64; d <<= 1) {
            u32 y = __shfl_up(x, (unsigned)d, 64);
            if (lane >= d) x += y;
        }
        if (lane == 63) wsum[wid] = x;
        __syncthreads();
        if (wid == 0) {
            u32 w = (lane < 16) ? wsum[lane] : 0u;
            #pragma unroll
            for (int d = 1; d < 16; d <<= 1) {
                u32 y = __shfl_up(w, (unsigned)d, 64);
                if (lane >= d) w += y;
            }
            if (lane < 16) wsum[lane] = w;
        }
        __syncthreads();
        u32 incl = x + (wid ? wsum[wid - 1] : 0u);
        u32 before = incl - s;
        if (before < RANK1 && incl >= RANK1) {
            u32 run = before;
            #pragma unroll
            for (int b = 0; b < 16; ++b) {
                run += h[b];
                if (run >= RANK1) { sB[0] = (u32)(tid * 16 + b); break; }
            }
        }
        if (before < TOPK && incl >= TOPK) {
            u32 run = before;
            #pragma unroll
            for (int b = 0; b < 16; ++b) {
                run += h[b];
                if (run >= TOPK) { sB[1] = (u32)(tid * 16 + b); break; }
            }
        }
        __syncthreads();
        const u32 B1 = sB[0], B2 = sB[1];

        u32 bin = fs >> 18;
        bool tryS = bin <= B1;
        u32 posS = 0xFFFFFFFFu;
        u64 mS = __ballot(tryS ? 1 : 0);
        if (mS) {
            int leader = __ffsll((unsigned long long)mS) - 1;
            u32 bb = 0;
            if (lane == leader) bb = atomicAdd(&cnt[0], (u32)__popcll(mS));
            bb = __shfl(bb, leader, 64);
            if (tryS) {
                posS = bb + (u32)__popcll(mS & ((1ull << lane) - 1ull));
                if (posS < SCAP) candS[posS] = key;
            }
        }
        bool toL = (bin <= B2) && (!tryS || posS >= SCAP);
        u64 mL = __ballot(toL ? 1 : 0);
        if (mL) {
            int leader = __ffsll((unsigned long long)mL) - 1;
            u32 bb = 0;
            if (lane == leader) bb = atomicAdd(&cnt[1], (u32)__popcll(mL));
            bb = __shfl(bb, leader, 64);
            if (toL) {
                u32 q = bb + (u32)__popcll(mL & ((1ull << lane) - 1ull));
                if (q < LCAP) candL[q] = key;
            }
        }
    }
    __threadfence();
    grid.sync();

    // ---- P3: serial core on block 0 only ----
    if (bid != 0) return;

    const u32 csRaw = cnt[0], clRaw = cnt[1];
    const u32 cs = csRaw < SCAP ? csRaw : SCAP;
    const u32 cl = clRaw < LCAP ? clRaw : LCAP;
    const bool fast = (csRaw <= SCAP);

    if (tid < 8) shu[tid] = 0;
    cand[tid] = ((u32)tid < cs) ? candS[tid] : ~0ull;
    __syncthreads();

    if (fast) {
        {   // in-wave bitonic stages k=2..64
            u64 v = cand[tid];
            #pragma unroll
            for (int k = 2; k <= 64; k <<= 1)
                #pragma unroll
                for (int j = k >> 1; j >= 1; j >>= 1)
                    v = ce64(v, j, lane, ((tid & k) == 0));
            cand[tid] = v;
        }
        __syncthreads();
        for (int k = 128; k <= SCAP; k <<= 1) {
            for (int j = k >> 1; j >= 64; j >>= 1) {
                if (tid < SCAP / 2) {
                    u32 i = ((tid & ~(j - 1)) << 1) | (tid & (j - 1));
                    u32 l = i | (u32)j;
                    bool up = ((i & (u32)k) == 0);
                    u64 a = cand[i], b = cand[l];
                    if ((a > b) == up) { cand[i] = b; cand[l] = a; }
                }
                __syncthreads();
            }
            {
                u64 v = cand[tid];
                bool up = (((wid * 64) & k) == 0);
                #pragma unroll
                for (int j = 32; j >= 1; j >>= 1) v = ce64(v, j, lane, up);
                cand[tid] = v;
            }
            __syncthreads();
        }

        // decode sorted S boxes + zero masks
        {
            u64 kk = cand[tid];
            if ((u32)tid < cs) {
                float4 b = decode_box(loc, anc, (u32)kk);
                sbox[tid] = b;
                sarea[tid] = (b.z - b.x) * (b.w - b.y);
            } else {
                sbox[tid] = make_float4(0.f, 0.f, 0.f, 0.f);
                sarea[tid] = 0.f;
            }
            for (int i = tid; i < MROWS * MW; i += 1024) ((u64*)smask)[i] = 0ull;
        }
        __syncthreads();

        // suppression matrix: row = t%MROWS (consecutive per lane), w = t/MROWS
        const u32 rowsv = cs < MROWS ? cs : MROWS;
        for (int t = tid; t < MROWS * MW; t += 1024) {
            int w = t / MROWS;
            int row = t - w * MROWS;
            int j0 = w * 64;
            int jmax = row < j0 + 64 ? row : j0 + 64;
            if (row < (int)rowsv && j0 < jmax) {
                float4 b = sbox[row];
                float ba = sarea[row];
                u64 m = 0;
                for (int j = j0; j < jmax; ++j)
                    if (iou_gt(b, ba, sbox[j], sarea[j])) m |= 1ull << (j - j0);
                smask[row][w] = m;
            }
        }
        __syncthreads();

        // greedy resolution on wave 0: bitmask ballot fixed point
        if (wid == 0) {
            u32 kc = 0, nexti0 = 0;
            u64 K[MW];
            #pragma unroll
            for (int w = 0; w < MW; ++w) K[w] = 0ull;
            #pragma unroll
            for (int cw = 0; cw < MW; ++cw) {
                u32 i0 = (u32)cw * 64u;
                if (i0 < rowsv && kc < OUTK) {
                    u32 ci = i0 + (u32)lane;
                    bool valid = ci < rowsv;
                    u64 myw[MW];
                    #pragma unroll
                    for (int w = 0; w < MW; ++w) myw[w] = valid ? smask[ci][w] : 0ull;
                    u64 supk = 0;
                    #pragma unroll
                    for (int w = 0; w < MW; ++w) supk |= myw[w] & K[w];
                    bool ia = valid && (supk == 0ull);
                    u64 inch = myw[cw] & ((1ull << lane) - 1ull);
                    u64 A = __ballot(ia ? 1 : 0);
                    for (int it = 0; it < 64; ++it) {
                        bool na = ia && ((inch & A) == 0ull);
                        u64 A2 = __ballot(na ? 1 : 0);
                        if (A2 == A) break;
                        A = A2;
                    }
                    bool kp = (A >> lane) & 1;
                    u32 rank = (u32)__popcll(A & ((1ull << lane) - 1ull));
                    if (kp && kc + rank < OUTK) {
                        float4 c = sbox[ci];
                        kept[kc + rank] = c;
                        karea[kc + rank] = sarea[ci];
                        out[kc + rank] = c;
                    }
                    K[cw] = A;
                    kc += (u32)__popcll(A);
                    nexti0 = i0 + 64;
                }
            }
            if (lane == 0) {
                shu[4] = kc > OUTK ? OUTK : kc;
                shu[5] = nexti0;
            }
        }

        // chunked NMS over remainder [nexti0, cs)
        const u32 limit = cs;
        while (true) {
            __syncthreads();
            u32 kc = shu[4], i0 = shu[5];
            if (kc >= OUTK || i0 >= limit) break;
            u32 ci = i0 + (u32)lane;
            bool valid = ci < limit;
            float4 c = sbox[valid ? ci : 0];
            float ca = sarea[valid ? ci : 0];

            bool sup = false;
            for (u32 j = (u32)wid; j < kc; j += 16)
                sup = sup || iou_gt(c, ca, kept[j], karea[j]);
            u64 bal = __ballot(sup ? 1 : 0);
            if (lane == 0) supw[wid] = bal;

            u64 sby = 0;
            u32 smax = 4u * wid + 4u; if (smax > 63u) smax = 63u;
            for (u32 s = 4u * wid + 1u; s <= smax; ++s) {
                u32 p = ((u32)lane + s) & 63u;
                if (p < (u32)lane && (i0 + p) < limit)
                    if (iou_gt(c, ca, sbox[i0 + p], sarea[i0 + p])) sby |= (1ull << p);
            }
            sbyp[wid * 64 + lane] = sby;
            __syncthreads();

            if (wid == 0) {
                u64 sup64 = 0, sbyfull = 0;
                #pragma unroll
                for (int w = 0; w < 16; ++w) { sup64 |= supw[w]; sbyfull |= sbyp[w * 64 + lane]; }
                bool ia = valid && !((sup64 >> lane) & 1);
                u64 A = __ballot(ia ? 1 : 0);
                for (int it = 0; it < 64; ++it) {
                    bool na = ia && ((sbyfull & A) == 0);
                    u64 A2 = __ballot(na ? 1 : 0);
                    if (A2 == A) break;
                    A = A2;
                }
                bool kp = (A >> lane) & 1;
                u32 rank = (u32)__popcll(A & ((1ull << lane) - 1ull));
                if (kp && kc + rank < OUTK) {
                    kept[kc + rank] = c; karea[kc + rank] = ca; out[kc + rank] = c;
                }
                if (lane == 0) {
                    u32 nk = kc + (u32)__popcll(A);
                    shu[4] = nk > OUTK ? OUTK : nk;
                    shu[5] = i0 + 64;
                }
            }
        }
    }

    // ---- Fallback: full 8192 sort over S+L + NMS w/ decode (rare) ----
    __syncthreads();
    const u32 kcF = shu[4];
    const u32 storedS = fast ? cs : SCAP;
    const u32 totalv = storedS + cl;
    const u32 limfb = totalv < TOPK ? totalv : TOPK;
    const u32 i0fb = fast ? cs : 0u;
    if (kcF < OUTK && i0fb < limfb) {
        for (int q = tid; q < LCAP; q += 1024)
            cand[SCAP + q] = ((u32)q < cl) ? candL[q] : ~0ull;
        __syncthreads();
        for (int seg = wid; seg < CAP / 64; seg += 16) {
            u64 v = cand[seg * 64 + lane];
            #pragma unroll
            for (int k = 2; k <= 64; k <<= 1)
                #pragma unroll
                for (int j = k >> 1; j >= 1; j >>= 1)
                    v = ce64(v, j, lane, (((seg * 64 + lane) & k) == 0));
            cand[seg * 64 + lane] = v;
        }
        __syncthreads();
        for (int k = 128; k <= CAP; k <<= 1) {
            for (int j = k >> 1; j >= 64; j >>= 1) {
                for (u32 p = (u32)tid; p < CAP / 2; p += 1024) {
                    u32 i = ((p & ~(u32)(j - 1)) << 1) | (p & (u32)(j - 1));
                    u32 l = i | (u32)j;
                    bool up = ((i & (u32)k) == 0);
                    u64 a = cand[i], b = cand[l];
                    if ((a > b) == up) { cand[i] = b; cand[l] = a; }
                }
                __syncthreads();
            }
            for (int seg = wid; seg < CAP / 64; seg += 16) {
                u64 v = cand[seg * 64 + lane];
                bool up = (((seg * 64) & k) == 0);
                #pragma unroll
                for (int j = 32; j >= 1; j >>= 1) v = ce64(v, j, lane, up);
                cand[seg * 64 + lane] = v;
            }
            __syncthreads();
        }
        if (tid == 0) shu[5] = i0fb;
        while (true) {
            __syncthreads();
            u32 kc = shu[4], i0 = shu[5];
            if (kc >= OUTK || i0 >= limfb) break;
            if (wid == 0) {
                u32 ci = i0 + (u32)lane;
                u32 n = (ci < limfb) ? (u32)cand[ci] : 0u;
                float4 b = decode_box(loc, anc, n);
                cbox[lane] = b;
                carea[lane] = (b.z - b.x) * (b.w - b.y);
            }
            __syncthreads();
            u32 ci = i0 + (u32)lane;
            bool valid = ci < limfb;
            float4 c = cbox[lane];
            float ca = carea[lane];
            bool sup = false;
            for (u32 j = (u32)wid; j < kc; j += 16)
                sup = sup || iou_gt(c, ca, kept[j], karea[j]);
            u64 bal = __ballot(sup ? 1 : 0);
            if (lane == 0) supw[wid] = bal;
            u64 sby = 0;
            u32 smax = 4u * wid + 4u; if (smax > 63u) smax = 63u;
            for (u32 s = 4u * wid + 1u; s <= smax; ++s) {
                u32 p = ((u32)lane + s) & 63u;
                if (p < (u32)lane && (i0 + p) < limfb)
                    if (iou_gt(c, ca, cbox[p], carea[p])) sby |= (1ull << p);
            }
            sbyp[wid * 64 + lane] = sby;
            __syncthreads();
            if (wid == 0) {
                u64 sup64 = 0, sbyfull = 0;
                #pragma unroll
                for (int w = 0; w < 16; ++w) { sup64 |= supw[w]; sbyfull |= sbyp[w * 64 + lane]; }
                bool ia = valid && !((sup64 >> lane) & 1);
                u64 A = __ballot(ia ? 1 : 0);
                for (int it = 0; it < 64; ++it) {
                    bool na = ia && ((sbyfull & A) == 0);
                    u64 A2 = __ballot(na ? 1 : 0);
                    if (A2 == A) break;
                    A = A2;
                }
                bool kp = (A >> lane) & 1;
                u32 rank = (u32)__popcll(A & ((1ull << lane) - 1ull));
                if (kp && kc + rank < OUTK) {
                    kept[kc + rank] = c; karea[kc + rank] = ca; out[kc + rank] = c;
                }
                if (lane == 0) {
                    u32 nk = kc + (u32)__popcll(A);
                    shu[4] = nk > OUTK ? OUTK : nk;
                    shu[5] = i0 + 64;
                }
            }
        }
    }

    // ---- zero-pad ----
    __syncthreads();
    u32 kc = shu[4];
    for (u32 r = (u32)tid; r < OUTK; r += 1024)
        if (r >= kc) out[r] = make_float4(0.f, 0.f, 0.f, 0.f);
}

extern "C" void kernel_launch(void* const* d_in, const int* in_sizes, int n_in,
                              void* d_out, int out_size, void* d_ws, size_t ws_size,
                              hipStream_t stream) {
    const float* cls = (const float*)d_in[0];   // (1, 18, 64, 96)
    const float* loc = (const float*)d_in[1];   // (1, 36, 64, 96)
    const float* anc = (const float*)d_in[2];   // (55296, 4)

    char* ws = (char*)d_ws;                     // needs 131,136 bytes
    u32* hist  = (u32*)(ws + 0);                // 65536 B (zeroed in P0)
    u32* cnt   = (u32*)(ws + 65536);            // 8 B     (zeroed in P0)
    u64* candS = (u64*)(ws + 65600);            // 8192 B
    u64* candL = (u64*)(ws + 73792);            // 57344 B
    float4* outp = (float4*)d_out;

    void* args[] = { (void*)&cls, (void*)&loc, (void*)&anc, (void*)&hist,
                     (void*)&cnt, (void*)&candS, (void*)&candL, (void*)&outp };
    hipLaunchCooperativeKernel((void*)k_all, dim3(NBLK), dim3(1024), args, 0, stream);
}

// Round 8
// 78.356 us; speedup vs baseline: 1.7198x; 1.7198x over previous
//
#include <hip/hip_runtime.h>

// RegionProposal: decode 55296 anchors -> stable top-6000 by score -> greedy
// NMS (IoU>0.7) -> first 300 kept boxes zero-padded to [300,4] fp32.
//
// Round-8: two kernels (R2's 66.8us structure, with all serial-core
// improvements from R4-R6 and zero per-element address math in the 1-CU
// kernel). Cooperative grid.sync (R7) measured ~30us/sync -> abandoned.
//
//  k_prep (54x1024): block b covers channel ch=b/6, elems e=(b%6)*1024+tid.
//    Coalesced: fs=flip32(cls[2ch+1][e]) -> fsarr[p], decoded box -> roi[p],
//    where p = b*1024+tid = ch*6144+e. All VALU (exp, clip) on 54 CUs ~ free.
//  k_core (1x1024): A: LDS 16384-bin hist of fsarr (54 coalesced reads/thr).
//    B: shuffle scan (3 barriers) -> B1=rank-512 bin, B2=rank-6000 bin.
//    C: ballot-aggregated compact: bin<=B1 -> LDS cand[] (keys), else<=B2 ->
//       global candL. Key=(fs<<32)|n, n=e*9+ch (anchor idx; exact stable
//       tie-break of argsort(-sigmoid)). No divisions (ch,e from unroll).
//    D: bitonic sort 1024 (in-wave k<=64 stages via shfl_xor + 10 LDS phases).
//    Gather sorted boxes from roi (n -> p = (n%9)*6144 + n/9).
//    E: 384x384 lower-tri suppression bitmask (conflict-free mapping),
//       ballot-greedy fixed point on wave 0, chunked NMS remainder,
//       early exit at 300 kept.
//    Fallback (ties/overflow, correctness only): full 8192 bitonic over
//       S+candL, chunked NMS with roi gather.
// IoU compare: fma-margin with exact-division fallback in +-1e-6 tie-zone ->
// bit-identical decisions to np reference (absmax 0.0, rounds 1-7).

#define ADIM 9
#define NANCH 55296
#define HWSZ 6144
#define TOPK 6000
#define OUTK 300
#define NBINS 16384
#define CAP 8192
#define SCAP 1024
#define LCAP 7168       // CAP - SCAP
#define RANK1 512
#define MROWS 384
#define MW 6            // MROWS/64
#define THR 0.7f

typedef unsigned long long u64;
typedef unsigned int u32;

__device__ __forceinline__ u32 flipu(u32 b) {
    u32 u = (b & 0x80000000u) ? ~b : (b | 0x80000000u);
    return ~u;                       // ascending result == descending float
}

__device__ __forceinline__ bool iou_gt(float4 a, float aa, float4 b, float ba) {
    float ix = fminf(a.z, b.z) - fmaxf(a.x, b.x);
    float iy = fminf(a.w, b.w) - fmaxf(a.y, b.y);
    float inter = fmaxf(ix, 0.f) * fmaxf(iy, 0.f);
    float u = fmaxf(aa + ba - inter, 1e-12f);
    float d = __builtin_fmaf(-THR, u, inter);           // inter - 0.7*u
    if (__builtin_fabsf(d) > 1e-6f * u) return d > 0.f; // sign-safe outside tie-zone
    return inter / u > THR;                             // exact IEEE div == np
}

__device__ __forceinline__ u64 sx64(u64 v, int m) {
    u32 lo = __shfl_xor((u32)(v & 0xffffffffu), m, 64);
    u32 hi = __shfl_xor((u32)(v >> 32), m, 64);
    return ((u64)hi << 32) | lo;
}

__device__ __forceinline__ u64 ce64(u64 v, int j, int lane, bool up) {
    u64 pv = sx64(v, j);
    u64 mn = (pv < v) ? pv : v;
    u64 mx = (pv < v) ? v : pv;
    return (((lane & j) == 0) == up) ? mn : mx;
}

// roi/fsarr storage index for anchor n
__device__ __forceinline__ u32 n_to_p(u32 n) {
    u32 q = n / 9u;                 // hw
    u32 rm = n - 9u * q;            // ch
    return rm * (u32)HWSZ + q;
}

// ---------------- K1: prep (coalesced fs + box decode) ----------------
__global__ void __launch_bounds__(1024) k_prep(const float* __restrict__ cls,
                                               const float* __restrict__ loc,
                                               const float* __restrict__ anc,
                                               u32* __restrict__ fsarr,
                                               float4* __restrict__ roi) {
    const int bid = blockIdx.x, tid = threadIdx.x;
    const int ch = bid / 6;
    const int e  = (bid - ch * 6) * 1024 + tid;
    const int p  = bid * 1024 + tid;          // == ch*HWSZ + e

    fsarr[p] = flipu(__float_as_uint(cls[(2 * ch + 1) * HWSZ + e]));

    const int n = e * ADIM + ch;
    float t0 = loc[(4 * ch + 0) * HWSZ + e];
    float t1 = loc[(4 * ch + 1) * HWSZ + e];
    float t2 = loc[(4 * ch + 2) * HWSZ + e];
    float t3 = loc[(4 * ch + 3) * HWSZ + e];
    float4 an = reinterpret_cast<const float4*>(anc)[n];
    float cx = t0 * an.z + an.x;
    float cy = t1 * an.w + an.y;
    float bw = expf(t2) * an.z;
    float bh = expf(t3) * an.w;
    roi[p] = make_float4(fminf(fmaxf(cx - bw * 0.5f, 0.f), 1.f),
                         fminf(fmaxf(cy - bh * 0.5f, 0.f), 1.f),
                         fminf(fmaxf(cx + bw * 0.5f, 0.f), 1.f),
                         fminf(fmaxf(cy + bh * 0.5f, 0.f), 1.f));
}

// ---------------- K2: single-block core ----------------
__global__ void __launch_bounds__(1024) k_core(const u32* __restrict__ fsarr,
                                               const float4* __restrict__ roi,
                                               u64* __restrict__ candL,
                                               float4* __restrict__ out) {
    __shared__ u64 cand[CAP];          // 64 KB; aliased u32 hist[16384] in A/B
    __shared__ float4 sbox[SCAP];      // 16 KB
    __shared__ float  sarea[SCAP];     // 4 KB
    __shared__ u64 smask[MROWS][MW];   // 18 KB
    __shared__ float4 kept[OUTK];
    __shared__ float  karea[OUTK];
    __shared__ float4 cbox[64];
    __shared__ float  carea[64];
    __shared__ u64 supw[16];
    __shared__ u64 sbyp[1024];         // 8 KB
    __shared__ u32 wsum[16];
    __shared__ u32 sB[2];
    __shared__ u32 shu[8];             // 0:cntS 1:cntL 4:kc 5:i0

    const int tid = threadIdx.x;
    const int wid = tid >> 6;
    const int lane = tid & 63;
    u32* hist = (u32*)cand;

    // ---- A: LDS histogram of fsarr ----
    for (int i = tid; i < NBINS; i += 1024) hist[i] = 0;
    if (tid < 8) shu[tid] = 0;
    __syncthreads();
    #pragma unroll
    for (int it = 0; it < NANCH / 1024; ++it)
        atomicAdd(&hist[fsarr[it * 1024 + tid] >> 18], 1u);
    __syncthreads();

    // ---- B: shuffle scan -> B1 (rank-512), B2 (rank-6000) ----
    {
        u32 h[16];
        const uint4* h4 = reinterpret_cast<const uint4*>(hist);
        #pragma unroll
        for (int k = 0; k < 4; ++k) {
            uint4 v = h4[tid * 4 + k];
            h[4 * k + 0] = v.x; h[4 * k + 1] = v.y; h[4 * k + 2] = v.z; h[4 * k + 3] = v.w;
        }
        u32 s = 0;
        #pragma unroll
        for (int b = 0; b < 16; ++b) s += h[b];
        u32 x = s;
        #pragma unroll
        for (int d = 1; d < 64; d <<= 1) {
            u32 y = __shfl_up(x, (unsigned)d, 64);
            if (lane >= d) x += y;
        }
        if (lane == 63) wsum[wid] = x;
        __syncthreads();
        if (wid == 0) {
            u32 w = (lane < 16) ? wsum[lane] : 0u;
            #pragma unroll
            for (int d = 1; d < 16; d <<= 1) {
                u32 y = __shfl_up(w, (unsigned)d, 64);
                if (lane >= d) w += y;
            }
            if (lane < 16) wsum[lane] = w;
        }
        __syncthreads();
        u32 incl = x + (wid ? wsum[wid - 1] : 0u);
        u32 before = incl - s;
        if (before < RANK1 && incl >= RANK1) {
            u32 run = before;
            #pragma unroll
            for (int b = 0; b < 16; ++b) {
                run += h[b];
                if (run >= RANK1) { sB[0] = (u32)(tid * 16 + b); break; }
            }
        }
        if (before < TOPK && incl >= TOPK) {
            u32 run = before;
            #pragma unroll
            for (int b = 0; b < 16; ++b) {
                run += h[b];
                if (run >= TOPK) { sB[1] = (u32)(tid * 16 + b); break; }
            }
        }
    }
    __syncthreads();
    const u32 B1 = sB[0], B2 = sB[1];
    __syncthreads();                   // everyone has B1/B2; hist now dead

    // ---- C: compact. S keys -> LDS cand, (B1,B2] -> global candL ----
    for (int i = tid; i < CAP; i += 1024) cand[i] = ~0ull;
    __syncthreads();
    #pragma unroll
    for (int ch = 0; ch < ADIM; ++ch) {
        #pragma unroll
        for (int r = 0; r < 6; ++r) {
            const int it = ch * 6 + r;
            u32 fs = fsarr[it * 1024 + tid];
            u32 bin = fs >> 18;
            u32 n = (u32)((r * 1024 + tid) * ADIM + ch);
            u64 key = ((u64)fs << 32) | n;
            bool tryS = bin <= B1;
            u32 posS = 0xFFFFFFFFu;
            u64 mS = __ballot(tryS ? 1 : 0);
            if (mS) {
                int leader = __ffsll((unsigned long long)mS) - 1;
                u32 bb = 0;
                if (lane == leader) bb = atomicAdd(&shu[0], (u32)__popcll(mS));
                bb = __shfl(bb, leader, 64);
                if (tryS) {
                    posS = bb + (u32)__popcll(mS & ((1ull << lane) - 1ull));
                    if (posS < SCAP) cand[posS] = key;
                }
            }
            bool toL = (bin <= B2) && (!tryS || posS >= SCAP);
            u64 mL = __ballot(toL ? 1 : 0);
            if (mL) {
                int leader = __ffsll((unsigned long long)mL) - 1;
                u32 bb = 0;
                if (lane == leader) bb = atomicAdd(&shu[1], (u32)__popcll(mL));
                bb = __shfl(bb, leader, 64);
                if (toL) {
                    u32 q = bb + (u32)__popcll(mL & ((1ull << lane) - 1ull));
                    if (q < LCAP) candL[q] = key;
                }
            }
        }
    }
    __syncthreads();
    const u32 csRaw = shu[0], clRaw = shu[1];
    const u32 cs = csRaw < SCAP ? csRaw : SCAP;
    const u32 cl = clRaw < LCAP ? clRaw : LCAP;
    const bool fast = (csRaw <= SCAP);

    // ---- D/E fast path ----
    if (fast) {
        {   // in-wave bitonic stages k=2..64
            u64 v = cand[tid];
            #pragma unroll
            for (int k = 2; k <= 64; k <<= 1)
                #pragma unroll
                for (int j = k >> 1; j >= 1; j >>= 1)
                    v = ce64(v, j, lane, ((tid & k) == 0));
            cand[tid] = v;
        }
        __syncthreads();
        for (int k = 128; k <= SCAP; k <<= 1) {
            for (int j = k >> 1; j >= 64; j >>= 1) {
                if (tid < SCAP / 2) {
                    u32 i = ((tid & ~(j - 1)) << 1) | (tid & (j - 1));
                    u32 l = i | (u32)j;
                    bool up = ((i & (u32)k) == 0);
                    u64 a = cand[i], b = cand[l];
                    if ((a > b) == up) { cand[i] = b; cand[l] = a; }
                }
                __syncthreads();
            }
            {
                u64 v = cand[tid];
                bool up = (((wid * 64) & k) == 0);
                #pragma unroll
                for (int j = 32; j >= 1; j >>= 1) v = ce64(v, j, lane, up);
                cand[tid] = v;
            }
            __syncthreads();
        }

        // gather sorted S boxes from roi + zero masks
        {
            u64 kk = cand[tid];
            if ((u32)tid < cs) {
                float4 b = roi[n_to_p((u32)kk)];
                sbox[tid] = b;
                sarea[tid] = (b.z - b.x) * (b.w - b.y);
            } else {
                sbox[tid] = make_float4(0.f, 0.f, 0.f, 0.f);
                sarea[tid] = 0.f;
            }
            for (int i = tid; i < MROWS * MW; i += 1024) ((u64*)smask)[i] = 0ull;
        }
        __syncthreads();

        // suppression matrix: row = t%MROWS (per-lane consecutive), w = t/MROWS
        const u32 rowsv = cs < MROWS ? cs : MROWS;
        for (int t = tid; t < MROWS * MW; t += 1024) {
            int w = t / MROWS;
            int row = t - w * MROWS;
            int j0 = w * 64;
            int jmax = row < j0 + 64 ? row : j0 + 64;
            if (row < (int)rowsv && j0 < jmax) {
                float4 b = sbox[row];
                float ba = sarea[row];
                u64 m = 0;
                for (int j = j0; j < jmax; ++j)
                    if (iou_gt(b, ba, sbox[j], sarea[j])) m |= 1ull << (j - j0);
                smask[row][w] = m;
            }
        }
        __syncthreads();

        // greedy resolution on wave 0: bitmask ballot fixed point
        if (wid == 0) {
            u32 kc = 0, nexti0 = 0;
            u64 K[MW];
            #pragma unroll
            for (int w = 0; w < MW; ++w) K[w] = 0ull;
            #pragma unroll
            for (int cw = 0; cw < MW; ++cw) {
                u32 i0 = (u32)cw * 64u;
                if (i0 < rowsv && kc < OUTK) {
                    u32 ci = i0 + (u32)lane;
                    bool valid = ci < rowsv;
                    u64 myw[MW];
                    #pragma unroll
                    for (int w = 0; w < MW; ++w) myw[w] = valid ? smask[ci][w] : 0ull;
                    u64 supk = 0;
                    #pragma unroll
                    for (int w = 0; w < MW; ++w) supk |= myw[w] & K[w];
                    bool ia = valid && (supk == 0ull);
                    u64 inch = myw[cw] & ((1ull << lane) - 1ull);
                    u64 A = __ballot(ia ? 1 : 0);
                    for (int itx = 0; itx < 64; ++itx) {
                        bool na = ia && ((inch & A) == 0ull);
                        u64 A2 = __ballot(na ? 1 : 0);
                        if (A2 == A) break;
                        A = A2;
                    }
                    bool kp = (A >> lane) & 1;
                    u32 rank = (u32)__popcll(A & ((1ull << lane) - 1ull));
                    if (kp && kc + rank < OUTK) {
                        float4 c = sbox[ci];
                        kept[kc + rank] = c;
                        karea[kc + rank] = sarea[ci];
                        out[kc + rank] = c;
                    }
                    K[cw] = A;
                    kc += (u32)__popcll(A);
                    nexti0 = i0 + 64;
                }
            }
            if (lane == 0) {
                shu[4] = kc > OUTK ? OUTK : kc;
                shu[5] = nexti0;
            }
        }

        // chunked NMS over remainder [nexti0, cs)
        const u32 limit = cs;
        while (true) {
            __syncthreads();
            u32 kc = shu[4], i0 = shu[5];
            if (kc >= OUTK || i0 >= limit) break;
            u32 ci = i0 + (u32)lane;
            bool valid = ci < limit;
            float4 c = sbox[valid ? ci : 0];
            float ca = sarea[valid ? ci : 0];

            bool sup = false;
            for (u32 j = (u32)wid; j < kc; j += 16)
                sup = sup || iou_gt(c, ca, kept[j], karea[j]);
            u64 bal = __ballot(sup ? 1 : 0);
            if (lane == 0) supw[wid] = bal;

            u64 sby = 0;
            u32 smax = 4u * wid + 4u; if (smax > 63u) smax = 63u;
            for (u32 s = 4u * wid + 1u; s <= smax; ++s) {
                u32 p = ((u32)lane + s) & 63u;
                if (p < (u32)lane && (i0 + p) < limit)
                    if (iou_gt(c, ca, sbox[i0 + p], sarea[i0 + p])) sby |= (1ull << p);
            }
            sbyp[wid * 64 + lane] = sby;
            __syncthreads();

            if (wid == 0) {
                u64 sup64 = 0, sbyfull = 0;
                #pragma unroll
                for (int w = 0; w < 16; ++w) { sup64 |= supw[w]; sbyfull |= sbyp[w * 64 + lane]; }
                bool ia = valid && !((sup64 >> lane) & 1);
                u64 A = __ballot(ia ? 1 : 0);
                for (int itx = 0; itx < 64; ++itx) {
                    bool na = ia && ((sbyfull & A) == 0);
                    u64 A2 = __ballot(na ? 1 : 0);
                    if (A2 == A) break;
                    A = A2;
                }
                bool kp = (A >> lane) & 1;
                u32 rank = (u32)__popcll(A & ((1ull << lane) - 1ull));
                if (kp && kc + rank < OUTK) {
                    kept[kc + rank] = c; karea[kc + rank] = ca; out[kc + rank] = c;
                }
                if (lane == 0) {
                    u32 nk = kc + (u32)__popcll(A);
                    shu[4] = nk > OUTK ? OUTK : nk;
                    shu[5] = i0 + 64;
                }
            }
        }
    }

    // ---- Fallback: full 8192 sort over S+candL + chunked NMS (rare) ----
    __syncthreads();
    const u32 kcF = shu[4];
    const u32 storedS = fast ? cs : SCAP;
    const u32 totalv = storedS + cl;
    const u32 limfb = totalv < TOPK ? totalv : TOPK;
    const u32 i0fb = fast ? cs : 0u;
    if (kcF < OUTK && i0fb < limfb) {
        for (int q = tid; q < LCAP; q += 1024)
            cand[SCAP + q] = ((u32)q < cl) ? candL[q] : ~0ull;
        __syncthreads();
        for (int seg = wid; seg < CAP / 64; seg += 16) {
            u64 v = cand[seg * 64 + lane];
            #pragma unroll
            for (int k = 2; k <= 64; k <<= 1)
                #pragma unroll
                for (int j = k >> 1; j >= 1; j >>= 1)
                    v = ce64(v, j, lane, (((seg * 64 + lane) & k) == 0));
            cand[seg * 64 + lane] = v;
        }
        __syncthreads();
        for (int k = 128; k <= CAP; k <<= 1) {
            for (int j = k >> 1; j >= 64; j >>= 1) {
                for (u32 p = (u32)tid; p < CAP / 2; p += 1024) {
                    u32 i = ((p & ~(u32)(j - 1)) << 1) | (p & (u32)(j - 1));
                    u32 l = i | (u32)j;
                    bool up = ((i & (u32)k) == 0);
                    u64 a = cand[i], b = cand[l];
                    if ((a > b) == up) { cand[i] = b; cand[l] = a; }
                }
                __syncthreads();
            }
            for (int seg = wid; seg < CAP / 64; seg += 16) {
                u64 v = cand[seg * 64 + lane];
                bool up = (((seg * 64) & k) == 0);
                #pragma unroll
                for (int j = 32; j >= 1; j >>= 1) v = ce64(v, j, lane, up);
                cand[seg * 64 + lane] = v;
            }
            __syncthreads();
        }
        if (tid == 0) shu[5] = i0fb;
        while (true) {
            __syncthreads();
            u32 kc = shu[4], i0 = shu[5];
            if (kc >= OUTK || i0 >= limfb) break;
            if (wid == 0) {
                u32 ci = i0 + (u32)lane;
                u32 n = (ci < limfb) ? (u32)cand[ci] : 0u;
                float4 b = roi[n_to_p(n)];
                cbox[lane] = b;
                carea[lane] = (b.z - b.x) * (b.w - b.y);
            }
            __syncthreads();
            u32 ci = i0 + (u32)lane;
            bool valid = ci < limfb;
            float4 c = cbox[lane];
            float ca = carea[lane];
            bool sup = false;
            for (u32 j = (u32)wid; j < kc; j += 16)
                sup = sup || iou_gt(c, ca, kept[j], karea[j]);
            u64 bal = __ballot(sup ? 1 : 0);
            if (lane == 0) supw[wid] = bal;
            u64 sby = 0;
            u32 smax = 4u * wid + 4u; if (smax > 63u) smax = 63u;
            for (u32 s = 4u * wid + 1u; s <= smax; ++s) {
                u32 p = ((u32)lane + s) & 63u;
                if (p < (u32)lane && (i0 + p) < limfb)
                    if (iou_gt(c, ca, cbox[p], carea[p])) sby |= (1ull << p);
            }
            sbyp[wid * 64 + lane] = sby;
            __syncthreads();
            if (wid == 0) {
                u64 sup64 = 0, sbyfull = 0;
                #pragma unroll
                for (int w = 0; w < 16; ++w) { sup64 |= supw[w]; sbyfull |= sbyp[w * 64 + lane]; }
                bool ia = valid && !((sup64 >> lane) & 1);
                u64 A = __ballot(ia ? 1 : 0);
                for (int itx = 0; itx < 64; ++itx) {
                    bool na = ia && ((sbyfull & A) == 0);
                    u64 A2 = __ballot(na ? 1 : 0);
                    if (A2 == A) break;
                    A = A2;
                }
                bool kp = (A >> lane) & 1;
                u32 rank = (u32)__popcll(A & ((1ull << lane) - 1ull));
                if (kp && kc + rank < OUTK) {
                    kept[kc + rank] = c; karea[kc + rank] = ca; out[kc + rank] = c;
                }
                if (lane == 0) {
                    u32 nk = kc + (u32)__popcll(A);
                    shu[4] = nk > OUTK ? OUTK : nk;
                    shu[5] = i0 + 64;
                }
            }
        }
    }

    // ---- zero-pad ----
    __syncthreads();
    u32 kc = shu[4];
    for (u32 r = (u32)tid; r < OUTK; r += 1024)
        if (r >= kc) out[r] = make_float4(0.f, 0.f, 0.f, 0.f);
}

extern "C" void kernel_launch(void* const* d_in, const int* in_sizes, int n_in,
                              void* d_out, int out_size, void* d_ws, size_t ws_size,
                              hipStream_t stream) {
    const float* cls = (const float*)d_in[0];   // (1, 18, 64, 96)
    const float* loc = (const float*)d_in[1];   // (1, 36, 64, 96)
    const float* anc = (const float*)d_in[2];   // (55296, 4)

    char* ws = (char*)d_ws;                     // needs 1,163,264 bytes
    u32*    fsarr = (u32*)(ws + 0);             // 221184 B
    float4* roi   = (float4*)(ws + 221184);     // 884736 B
    u64*    candL = (u64*)(ws + 1105920);       // 57344 B

    k_prep<<<NANCH / 1024, 1024, 0, stream>>>(cls, loc, anc, fsarr, roi);
    k_core<<<1, 1024, 0, stream>>>(fsarr, roi, candL, (float4*)d_out);
}

// Round 9
// 68.629 us; speedup vs baseline: 1.9636x; 1.1417x over previous
//
#include <hip/hip_runtime.h>

// RegionProposal: decode 55296 anchors -> stable top-6000 by score -> greedy
// NMS (IoU>0.7) -> first 300 kept boxes zero-padded to [300,4] fp32.
//
// Round-9: two kernels. vs R8: phases A/C use batched uint4 loads (R4-proven),
// and the 1024-slot bitonic sort is replaced by a counting-rank sort
// (rank = #{smaller keys}, one barrier-free O(cs^2/1024) LDS-broadcast pass,
// then scatter key+box to sorted position). Matrix NMS unchanged from R8.
//
//  k_prep (54x1024): block b -> channel ch=b/6, elems e=(b%6)*1024+tid; all
//    coalesced. fs=flip32(cls[2ch+1][e]) -> fsarr[p], decoded box -> roi[p],
//    p = b*1024+tid = ch*6144+e.
//  k_core (1x1024):
//    A: LDS 16384-bin hist of fsarr (2 batches x 7 uint4 loads).
//    B: shuffle scan (3 barriers) -> B1=rank-512 bin, B2=rank-6000 bin.
//    C: batched uint4 re-read + ballot-aggregated append: bin<=B1 -> LDS
//       skey[], else<=B2 -> global candL. key=(fs<<32)|n, n=e*9+ch.
//    D: counting-rank: t<cs: rank=#{j: skey[j]<skey[t]} (wave-uniform LDS
//       broadcast reads); cand[rank]=key; sbox/sarea[rank]=roi[n_to_p(key)].
//    E: 384x384 lower-tri suppression bitmask, ballot-greedy fixed point on
//       wave 0, chunked NMS remainder, early exit at 300 kept.
//    Fallback (ties/overflow; correctness only): full 8192 bitonic over
//       S+candL, chunked NMS with roi gather.
// IoU compare: fma-margin with exact-division fallback in +-1e-6 tie-zone ->
// bit-identical decisions to np reference (absmax 0.0, rounds 1-8).

#define ADIM 9
#define NANCH 55296
#define HWSZ 6144
#define CH_U4 1536      // HWSZ/4
#define TOT_U4 13824    // 9 * CH_U4
#define TOPK 6000
#define OUTK 300
#define NBINS 16384
#define CAP 8192
#define SCAP 1024
#define LCAP 7168       // CAP - SCAP
#define RANK1 512
#define MROWS 384
#define MW 6            // MROWS/64
#define THR 0.7f

typedef unsigned long long u64;
typedef unsigned int u32;

__device__ __forceinline__ u32 flipu(u32 b) {
    u32 u = (b & 0x80000000u) ? ~b : (b | 0x80000000u);
    return ~u;                       // ascending result == descending float
}

__device__ __forceinline__ bool iou_gt(float4 a, float aa, float4 b, float ba) {
    float ix = fminf(a.z, b.z) - fmaxf(a.x, b.x);
    float iy = fminf(a.w, b.w) - fmaxf(a.y, b.y);
    float inter = fmaxf(ix, 0.f) * fmaxf(iy, 0.f);
    float u = fmaxf(aa + ba - inter, 1e-12f);
    float d = __builtin_fmaf(-THR, u, inter);           // inter - 0.7*u
    if (__builtin_fabsf(d) > 1e-6f * u) return d > 0.f; // sign-safe outside tie-zone
    return inter / u > THR;                             // exact IEEE div == np
}

__device__ __forceinline__ u64 sx64(u64 v, int m) {
    u32 lo = __shfl_xor((u32)(v & 0xffffffffu), m, 64);
    u32 hi = __shfl_xor((u32)(v >> 32), m, 64);
    return ((u64)hi << 32) | lo;
}

__device__ __forceinline__ u64 ce64(u64 v, int j, int lane, bool up) {
    u64 pv = sx64(v, j);
    u64 mn = (pv < v) ? pv : v;
    u64 mx = (pv < v) ? v : pv;
    return (((lane & j) == 0) == up) ? mn : mx;
}

// roi/fsarr storage index for anchor n
__device__ __forceinline__ u32 n_to_p(u32 n) {
    u32 q = n / 9u;                 // hw
    u32 rm = n - 9u * q;            // ch
    return rm * (u32)HWSZ + q;
}

// ---------------- K1: prep (coalesced fs + box decode) ----------------
__global__ void __launch_bounds__(1024) k_prep(const float* __restrict__ cls,
                                               const float* __restrict__ loc,
                                               const float* __restrict__ anc,
                                               u32* __restrict__ fsarr,
                                               float4* __restrict__ roi) {
    const int bid = blockIdx.x, tid = threadIdx.x;
    const int ch = bid / 6;
    const int e  = (bid - ch * 6) * 1024 + tid;
    const int p  = bid * 1024 + tid;          // == ch*HWSZ + e

    fsarr[p] = flipu(__float_as_uint(cls[(2 * ch + 1) * HWSZ + e]));

    const int n = e * ADIM + ch;
    float t0 = loc[(4 * ch + 0) * HWSZ + e];
    float t1 = loc[(4 * ch + 1) * HWSZ + e];
    float t2 = loc[(4 * ch + 2) * HWSZ + e];
    float t3 = loc[(4 * ch + 3) * HWSZ + e];
    float4 an = reinterpret_cast<const float4*>(anc)[n];
    float cx = t0 * an.z + an.x;
    float cy = t1 * an.w + an.y;
    float bw = expf(t2) * an.z;
    float bh = expf(t3) * an.w;
    roi[p] = make_float4(fminf(fmaxf(cx - bw * 0.5f, 0.f), 1.f),
                         fminf(fmaxf(cy - bh * 0.5f, 0.f), 1.f),
                         fminf(fmaxf(cx + bw * 0.5f, 0.f), 1.f),
                         fminf(fmaxf(cy + bh * 0.5f, 0.f), 1.f));
}

// ---------------- K2: single-block core ----------------
__global__ void __launch_bounds__(1024) k_core(const u32* __restrict__ fsarr,
                                               const float4* __restrict__ roi,
                                               u64* __restrict__ candL,
                                               float4* __restrict__ out) {
    __shared__ u64 cand[CAP];          // 64 KB; aliased u32 hist[16384] in A/B
    __shared__ u64 skey[SCAP];         // 8 KB unsorted S keys
    __shared__ float4 sbox[SCAP];      // 16 KB (sorted boxes)
    __shared__ float  sarea[SCAP];     // 4 KB
    __shared__ u64 smask[MROWS][MW];   // 18 KB
    __shared__ float4 kept[OUTK];
    __shared__ float  karea[OUTK];
    __shared__ float4 cbox[64];
    __shared__ float  carea[64];
    __shared__ u64 supw[16];
    __shared__ u64 sbyp[1024];         // 8 KB
    __shared__ u32 wsum[16];
    __shared__ u32 sB[2];
    __shared__ u32 shu[8];             // 0:cntS 1:cntL 4:kc 5:i0

    const int tid = threadIdx.x;
    const int wid = tid >> 6;
    const int lane = tid & 63;
    u32* hist = (u32*)cand;
    const uint4* f4 = reinterpret_cast<const uint4*>(fsarr);

    // ---- A: LDS histogram (batched uint4 loads) ----
    for (int i = tid; i < NBINS; i += 1024) hist[i] = 0;
    if (tid < 8) shu[tid] = 0;
    __syncthreads();
    #pragma unroll
    for (int half = 0; half < 2; ++half) {
        uint4 buf[7];
        #pragma unroll
        for (int kk = 0; kk < 7; ++kk) {
            int i = (half * 7 + kk) * 1024 + tid;
            buf[kk] = (i < TOT_U4) ? f4[i] : make_uint4(0u, 0u, 0u, 0u);
        }
        #pragma unroll
        for (int kk = 0; kk < 7; ++kk) {
            int i = (half * 7 + kk) * 1024 + tid;
            if (i < TOT_U4) {
                atomicAdd(&hist[buf[kk].x >> 18], 1u);
                atomicAdd(&hist[buf[kk].y >> 18], 1u);
                atomicAdd(&hist[buf[kk].z >> 18], 1u);
                atomicAdd(&hist[buf[kk].w >> 18], 1u);
            }
        }
    }
    __syncthreads();

    // ---- B: shuffle scan -> B1 (rank-512), B2 (rank-6000) ----
    {
        u32 h[16];
        const uint4* h4 = reinterpret_cast<const uint4*>(hist);
        #pragma unroll
        for (int k = 0; k < 4; ++k) {
            uint4 v = h4[tid * 4 + k];
            h[4 * k + 0] = v.x; h[4 * k + 1] = v.y; h[4 * k + 2] = v.z; h[4 * k + 3] = v.w;
        }
        u32 s = 0;
        #pragma unroll
        for (int b = 0; b < 16; ++b) s += h[b];
        u32 x = s;
        #pragma unroll
        for (int d = 1; d < 64; d <<= 1) {
            u32 y = __shfl_up(x, (unsigned)d, 64);
            if (lane >= d) x += y;
        }
        if (lane == 63) wsum[wid] = x;
        __syncthreads();
        if (wid == 0) {
            u32 w = (lane < 16) ? wsum[lane] : 0u;
            #pragma unroll
            for (int d = 1; d < 16; d <<= 1) {
                u32 y = __shfl_up(w, (unsigned)d, 64);
                if (lane >= d) w += y;
            }
            if (lane < 16) wsum[lane] = w;
        }
        __syncthreads();
        u32 incl = x + (wid ? wsum[wid - 1] : 0u);
        u32 before = incl - s;
        if (before < RANK1 && incl >= RANK1) {
            u32 run = before;
            #pragma unroll
            for (int b = 0; b < 16; ++b) {
                run += h[b];
                if (run >= RANK1) { sB[0] = (u32)(tid * 16 + b); break; }
            }
        }
        if (before < TOPK && incl >= TOPK) {
            u32 run = before;
            #pragma unroll
            for (int b = 0; b < 16; ++b) {
                run += h[b];
                if (run >= TOPK) { sB[1] = (u32)(tid * 16 + b); break; }
            }
        }
    }
    __syncthreads();
    const u32 B1 = sB[0], B2 = sB[1];
    __syncthreads();                   // hist dead below this point

    // ---- C: init cand/smask; batched compact -> skey (LDS) / candL (global) ----
    for (int i = tid; i < CAP; i += 1024) cand[i] = ~0ull;
    for (int i = tid; i < MROWS * MW; i += 1024) ((u64*)smask)[i] = 0ull;
    __syncthreads();
    #pragma unroll
    for (int half = 0; half < 2; ++half) {
        uint4 buf[7];
        #pragma unroll
        for (int kk = 0; kk < 7; ++kk) {
            int i = (half * 7 + kk) * 1024 + tid;
            buf[kk] = (i < TOT_U4) ? f4[i] : make_uint4(0u, 0u, 0u, 0u);
        }
        #pragma unroll
        for (int kk = 0; kk < 7; ++kk) {
            int i = (half * 7 + kk) * 1024 + tid;
            bool v = i < TOT_U4;
            int ch = i / CH_U4;
            int e0 = (i - ch * CH_U4) * 4;
            u32 n0 = (u32)(e0 * ADIM + ch);
            #pragma unroll
            for (int c = 0; c < 4; ++c) {
                u32 fs = (c == 0) ? buf[kk].x : (c == 1) ? buf[kk].y
                       : (c == 2) ? buf[kk].z : buf[kk].w;
                u32 bin = fs >> 18;
                u64 key = ((u64)fs << 32) | (n0 + 9u * (u32)c);
                bool tryS = v && (bin <= B1);
                u32 posS = 0xFFFFFFFFu;
                u64 mS = __ballot(tryS ? 1 : 0);
                if (mS) {
                    int leader = __ffsll((unsigned long long)mS) - 1;
                    u32 bb = 0;
                    if (lane == leader) bb = atomicAdd(&shu[0], (u32)__popcll(mS));
                    bb = __shfl(bb, leader, 64);
                    if (tryS) {
                        posS = bb + (u32)__popcll(mS & ((1ull << lane) - 1ull));
                        if (posS < SCAP) skey[posS] = key;
                    }
                }
                bool toL = v && (bin <= B2) && (!tryS || posS >= SCAP);
                u64 mL = __ballot(toL ? 1 : 0);
                if (mL) {
                    int leader = __ffsll((unsigned long long)mL) - 1;
                    u32 bb = 0;
                    if (lane == leader) bb = atomicAdd(&shu[1], (u32)__popcll(mL));
                    bb = __shfl(bb, leader, 64);
                    if (toL) {
                        u32 q = bb + (u32)__popcll(mL & ((1ull << lane) - 1ull));
                        if (q < LCAP) candL[q] = key;
                    }
                }
            }
        }
    }
    __syncthreads();
    const u32 csRaw = shu[0], clRaw = shu[1];
    const u32 cs = csRaw < SCAP ? csRaw : SCAP;
    const u32 cl = clRaw < LCAP ? clRaw : LCAP;
    const bool fast = (csRaw <= SCAP);

    // ---- D/E fast path ----
    if (fast) {
        // counting-rank sort + gather: rank = #{j: skey[j] < mine}
        if ((u32)tid < cs) {
            u64 myk = skey[tid];
            float4 b = roi[n_to_p((u32)myk)];     // latency hides under rank loop
            u32 rank = 0;
            for (u32 j = 0; j < cs; ++j)
                rank += (skey[j] < myk) ? 1u : 0u;   // wave-uniform broadcast read
            cand[rank] = myk;
            sbox[rank] = b;
            sarea[rank] = (b.z - b.x) * (b.w - b.y);
        }
        __syncthreads();

        // suppression matrix: row = t%MROWS (per-lane consecutive), w = t/MROWS
        const u32 rowsv = cs < MROWS ? cs : MROWS;
        for (int t = tid; t < MROWS * MW; t += 1024) {
            int w = t / MROWS;
            int row = t - w * MROWS;
            int j0 = w * 64;
            int jmax = row < j0 + 64 ? row : j0 + 64;
            if (row < (int)rowsv && j0 < jmax) {
                float4 b = sbox[row];
                float ba = sarea[row];
                u64 m = 0;
                for (int j = j0; j < jmax; ++j)
                    if (iou_gt(b, ba, sbox[j], sarea[j])) m |= 1ull << (j - j0);
                smask[row][w] = m;
            }
        }
        __syncthreads();

        // greedy resolution on wave 0: bitmask ballot fixed point
        if (wid == 0) {
            u32 kc = 0, nexti0 = 0;
            u64 K[MW];
            #pragma unroll
            for (int w = 0; w < MW; ++w) K[w] = 0ull;
            #pragma unroll
            for (int cw = 0; cw < MW; ++cw) {
                u32 i0 = (u32)cw * 64u;
                if (i0 < rowsv && kc < OUTK) {
                    u32 ci = i0 + (u32)lane;
                    bool valid = ci < rowsv;
                    u64 myw[MW];
                    #pragma unroll
                    for (int w = 0; w < MW; ++w) myw[w] = valid ? smask[ci][w] : 0ull;
                    u64 supk = 0;
                    #pragma unroll
                    for (int w = 0; w < MW; ++w) supk |= myw[w] & K[w];
                    bool ia = valid && (supk == 0ull);
                    u64 inch = myw[cw] & ((1ull << lane) - 1ull);
                    u64 A = __ballot(ia ? 1 : 0);
                    for (int itx = 0; itx < 64; ++itx) {
                        bool na = ia && ((inch & A) == 0ull);
                        u64 A2 = __ballot(na ? 1 : 0);
                        if (A2 == A) break;
                        A = A2;
                    }
                    bool kp = (A >> lane) & 1;
                    u32 rank = (u32)__popcll(A & ((1ull << lane) - 1ull));
                    if (kp && kc + rank < OUTK) {
                        float4 c = sbox[ci];
                        kept[kc + rank] = c;
                        karea[kc + rank] = sarea[ci];
                        out[kc + rank] = c;
                    }
                    K[cw] = A;
                    kc += (u32)__popcll(A);
                    nexti0 = i0 + 64;
                }
            }
            if (lane == 0) {
                shu[4] = kc > OUTK ? OUTK : kc;
                shu[5] = nexti0;
            }
        }

        // chunked NMS over remainder [nexti0, cs) (dead for typical inputs)
        const u32 limit = cs;
        while (true) {
            __syncthreads();
            u32 kc = shu[4], i0 = shu[5];
            if (kc >= OUTK || i0 >= limit) break;
            u32 ci = i0 + (u32)lane;
            bool valid = ci < limit;
            float4 c = sbox[valid ? ci : 0];
            float ca = sarea[valid ? ci : 0];

            bool sup = false;
            for (u32 j = (u32)wid; j < kc; j += 16)
                sup = sup || iou_gt(c, ca, kept[j], karea[j]);
            u64 bal = __ballot(sup ? 1 : 0);
            if (lane == 0) supw[wid] = bal;

            u64 sby = 0;
            u32 smax = 4u * wid + 4u; if (smax > 63u) smax = 63u;
            for (u32 s = 4u * wid + 1u; s <= smax; ++s) {
                u32 p = ((u32)lane + s) & 63u;
                if (p < (u32)lane && (i0 + p) < limit)
                    if (iou_gt(c, ca, sbox[i0 + p], sarea[i0 + p])) sby |= (1ull << p);
            }
            sbyp[wid * 64 + lane] = sby;
            __syncthreads();

            if (wid == 0) {
                u64 sup64 = 0, sbyfull = 0;
                #pragma unroll
                for (int w = 0; w < 16; ++w) { sup64 |= supw[w]; sbyfull |= sbyp[w * 64 + lane]; }
                bool ia = valid && !((sup64 >> lane) & 1);
                u64 A = __ballot(ia ? 1 : 0);
                for (int itx = 0; itx < 64; ++itx) {
                    bool na = ia && ((sbyfull & A) == 0);
                    u64 A2 = __ballot(na ? 1 : 0);
                    if (A2 == A) break;
                    A = A2;
                }
                bool kp = (A >> lane) & 1;
                u32 rank = (u32)__popcll(A & ((1ull << lane) - 1ull));
                if (kp && kc + rank < OUTK) {
                    kept[kc + rank] = c; karea[kc + rank] = ca; out[kc + rank] = c;
                }
                if (lane == 0) {
                    u32 nk = kc + (u32)__popcll(A);
                    shu[4] = nk > OUTK ? OUTK : nk;
                    shu[5] = i0 + 64;
                }
            }
        }
    } else {
        cand[tid] = skey[tid];   // all SCAP slots written when csRaw > SCAP
    }

    // ---- Fallback: full 8192 sort over S+candL + chunked NMS (rare) ----
    __syncthreads();
    const u32 kcF = shu[4];
    const u32 storedS = fast ? cs : SCAP;
    const u32 totalv = storedS + cl;
    const u32 limfb = totalv < TOPK ? totalv : TOPK;
    const u32 i0fb = fast ? cs : 0u;
    if (kcF < OUTK && i0fb < limfb) {
        for (int q = tid; q < LCAP; q += 1024)
            cand[SCAP + q] = ((u32)q < cl) ? candL[q] : ~0ull;
        __syncthreads();
        for (int seg = wid; seg < CAP / 64; seg += 16) {
            u64 v = cand[seg * 64 + lane];
            #pragma unroll
            for (int k = 2; k <= 64; k <<= 1)
                #pragma unroll
                for (int j = k >> 1; j >= 1; j >>= 1)
                    v = ce64(v, j, lane, (((seg * 64 + lane) & k) == 0));
            cand[seg * 64 + lane] = v;
        }
        __syncthreads();
        for (int k = 128; k <= CAP; k <<= 1) {
            for (int j = k >> 1; j >= 64; j >>= 1) {
                for (u32 p = (u32)tid; p < CAP / 2; p += 1024) {
                    u32 i = ((p & ~(u32)(j - 1)) << 1) | (p & (u32)(j - 1));
                    u32 l = i | (u32)j;
                    bool up = ((i & (u32)k) == 0);
                    u64 a = cand[i], b = cand[l];
                    if ((a > b) == up) { cand[i] = b; cand[l] = a; }
                }
                __syncthreads();
            }
            for (int seg = wid; seg < CAP / 64; seg += 16) {
                u64 v = cand[seg * 64 + lane];
                bool up = (((seg * 64) & k) == 0);
                #pragma unroll
                for (int j = 32; j >= 1; j >>= 1) v = ce64(v, j, lane, up);
                cand[seg * 64 + lane] = v;
            }
            __syncthreads();
        }
        if (tid == 0) shu[5] = i0fb;
        while (true) {
            __syncthreads();
            u32 kc = shu[4], i0 = shu[5];
            if (kc >= OUTK || i0 >= limfb) break;
            if (wid == 0) {
                u32 ci = i0 + (u32)lane;
                u32 n = (ci < limfb) ? (u32)cand[ci] : 0u;
                float4 b = roi[n_to_p(n)];
                cbox[lane] = b;
                carea[lane] = (b.z - b.x) * (b.w - b.y);
            }
            __syncthreads();
            u32 ci = i0 + (u32)lane;
            bool valid = ci < limfb;
            float4 c = cbox[lane];
            float ca = carea[lane];
            bool sup = false;
            for (u32 j = (u32)wid; j < kc; j += 16)
                sup = sup || iou_gt(c, ca, kept[j], karea[j]);
            u64 bal = __ballot(sup ? 1 : 0);
            if (lane == 0) supw[wid] = bal;
            u64 sby = 0;
            u32 smax = 4u * wid + 4u; if (smax > 63u) smax = 63u;
            for (u32 s = 4u * wid + 1u; s <= smax; ++s) {
                u32 p = ((u32)lane + s) & 63u;
                if (p < (u32)lane && (i0 + p) < limfb)
                    if (iou_gt(c, ca, cbox[p], carea[p])) sby |= (1ull << p);
            }
            sbyp[wid * 64 + lane] = sby;
            __syncthreads();
            if (wid == 0) {
                u64 sup64 = 0, sbyfull = 0;
                #pragma unroll
                for (int w = 0; w < 16; ++w) { sup64 |= supw[w]; sbyfull |= sbyp[w * 64 + lane]; }
                bool ia = valid && !((sup64 >> lane) & 1);
                u64 A = __ballot(ia ? 1 : 0);
                for (int itx = 0; itx < 64; ++itx) {
                    bool na = ia && ((sbyfull & A) == 0);
                    u64 A2 = __ballot(na ? 1 : 0);
                    if (A2 == A) break;
                    A = A2;
                }
                bool kp = (A >> lane) & 1;
                u32 rank = (u32)__popcll(A & ((1ull << lane) - 1ull));
                if (kp && kc + rank < OUTK) {
                    kept[kc + rank] = c; karea[kc + rank] = ca; out[kc + rank] = c;
                }
                if (lane == 0) {
                    u32 nk = kc + (u32)__popcll(A);
                    shu[4] = nk > OUTK ? OUTK : nk;
                    shu[5] = i0 + 64;
                }
            }
        }
    }

    // ---- zero-pad ----
    __syncthreads();
    u32 kc = shu[4];
    for (u32 r = (u32)tid; r < OUTK; r += 1024)
        if (r >= kc) out[r] = make_float4(0.f, 0.f, 0.f, 0.f);
}

extern "C" void kernel_launch(void* const* d_in, const int* in_sizes, int n_in,
                              void* d_out, int out_size, void* d_ws, size_t ws_size,
                              hipStream_t stream) {
    const float* cls = (const float*)d_in[0];   // (1, 18, 64, 96)
    const float* loc = (const float*)d_in[1];   // (1, 36, 64, 96)
    const float* anc = (const float*)d_in[2];   // (55296, 4)

    char* ws = (char*)d_ws;                     // needs 1,163,264 bytes
    u32*    fsarr = (u32*)(ws + 0);             // 221184 B
    float4* roi   = (float4*)(ws + 221184);     // 884736 B
    u64*    candL = (u64*)(ws + 1105920);       // 57344 B

    k_prep<<<NANCH / 1024, 1024, 0, stream>>>(cls, loc, anc, fsarr, roi);
    k_core<<<1, 1024, 0, stream>>>(fsarr, roi, candL, (float4*)d_out);
}

// Round 10
// 65.873 us; speedup vs baseline: 2.0457x; 1.0418x over previous
//
#include <hip/hip_runtime.h>

// RegionProposal: decode 55296 anchors -> stable top-6000 by score -> greedy
// NMS (IoU>0.7) -> first 300 kept boxes zero-padded to [300,4] fp32.
//
// Round-10: ONE kernel (1x1024), everything in LDS/registers.
//  A': zero 16384-bin hist; histogram a 1/4 systematic sample (every 4th
//      uint4) of fs=flip32(class-1 logit). B1' = sampled-rank-128 bin.
//      (B1 is a correctness-free knob: greedy NMS's first-300-kept depends
//      only on the sorted order; any certified prefix with >=300 kept gives
//      the identical output. True count(<=B1') ~ 512 +- 40, always >= 128.)
//  C : count pass over all cls values (batched uint4, registers) with
//      per-thread candidate bitmask -> block scan -> write pass (reload only
//      uint4s containing candidates) -> sfs/sidx LDS arrays. No atomics.
//  D : distributed counting-rank: 256 cand-groups x 4 j-quarters, b128 reads
//      of fs, partial ranks combined via LDS atomicAdd. Rank-collision
//      (atomicExch flag) detects fs ties -> exact (fs,idx) re-rank path.
//      Scatter: decode candidate boxes on demand -> sbox[rank].
//  E : wave-tiled 384x384 lower-tri suppression bitmask (lane=row in regs,
//      sbox[j] broadcast shared by 64 rows), ballot-greedy fixed point on
//      wave 0, chunked NMS remainder, early exit at 300 kept.
//  Fallback (cs>1024 / <300 kept; rare, correctness only): exact full
//      histogram -> exact rank-6000 bin B2 -> scan-compact all <=B2 into
//      cand[8192] -> bitonic sort -> chunked NMS with on-demand decode,
//      continuing from the already-consumed prefix (B1' <= B2 so the fast
//      path's cs candidates are exactly the first cs of the full order).
//
// Key = (fs<<32)|n, n=anchor idx: ascending == descending logit, ties by
// ascending index == stable argsort(-sigmoid(logit)). IoU compare: fma-margin
// with exact-division fallback in the +-1e-6 tie-zone -> decisions
// bit-identical to the np reference (absmax 0.0, rounds 1-9).

#define ADIM 9
#define NANCH 55296
#define HWSZ 6144
#define CH_U4 1536      // HWSZ/4
#define TOT_U4 13824    // ADIM * CH_U4
#define SAMP_U4 3456    // TOT_U4/4
#define TOPK 6000
#define OUTK 300
#define NBINS 16384
#define CAP 8192
#define SCAP 1024
#define SRANK 128       // sampled rank target for B1'
#define MROWS 384
#define MW 6            // MROWS/64
#define NTILE 21        // MW*(MW+1)/2
#define THR 0.7f

typedef unsigned long long u64;
typedef unsigned int u32;

__device__ __forceinline__ u32 flipu(u32 b) {
    u32 u = (b & 0x80000000u) ? ~b : (b | 0x80000000u);
    return ~u;                       // ascending result == descending float
}

__device__ __forceinline__ bool iou_gt(float4 a, float aa, float4 b, float ba) {
    float ix = fminf(a.z, b.z) - fmaxf(a.x, b.x);
    float iy = fminf(a.w, b.w) - fmaxf(a.y, b.y);
    float inter = fmaxf(ix, 0.f) * fmaxf(iy, 0.f);
    float u = fmaxf(aa + ba - inter, 1e-12f);
    float d = __builtin_fmaf(-THR, u, inter);           // inter - 0.7*u
    if (__builtin_fabsf(d) > 1e-6f * u) return d > 0.f; // sign-safe outside tie-zone
    return inter / u > THR;                             // exact IEEE div == np
}

__device__ __forceinline__ float4 decode_box(const float* __restrict__ loc,
                                             const float* __restrict__ anc, u32 n) {
    u32 a = n % 9u, hw = n / 9u;
    float t0 = loc[(4 * a + 0) * HWSZ + hw];
    float t1 = loc[(4 * a + 1) * HWSZ + hw];
    float t2 = loc[(4 * a + 2) * HWSZ + hw];
    float t3 = loc[(4 * a + 3) * HWSZ + hw];
    float4 an = reinterpret_cast<const float4*>(anc)[n];
    float cx = t0 * an.z + an.x;
    float cy = t1 * an.w + an.y;
    float bw = expf(t2) * an.z;
    float bh = expf(t3) * an.w;
    return make_float4(fminf(fmaxf(cx - bw * 0.5f, 0.f), 1.f),
                       fminf(fmaxf(cy - bh * 0.5f, 0.f), 1.f),
                       fminf(fmaxf(cx + bw * 0.5f, 0.f), 1.f),
                       fminf(fmaxf(cy + bh * 0.5f, 0.f), 1.f));
}

__device__ __forceinline__ u64 sx64(u64 v, int m) {
    u32 lo = __shfl_xor((u32)(v & 0xffffffffu), m, 64);
    u32 hi = __shfl_xor((u32)(v >> 32), m, 64);
    return ((u64)hi << 32) | lo;
}

__device__ __forceinline__ u64 ce64(u64 v, int j, int lane, bool up) {
    u64 pv = sx64(v, j);
    u64 mn = (pv < v) ? pv : v;
    u64 mx = (pv < v) ? v : pv;
    return (((lane & j) == 0) == up) ? mn : mx;
}

// load the i-th class-1 uint4 (i in [0, TOT_U4))
__device__ __forceinline__ uint4 ld_cls4(const uint4* __restrict__ cls4, int i) {
    int ch = i / CH_U4;
    int e4 = i - ch * CH_U4;
    return cls4[(2 * ch + 1) * CH_U4 + e4];
}

// block inclusive scan of per-thread u32; returns inclusive; total in wsum[15]
__device__ __forceinline__ u32 block_scan(u32 s, int wid, int lane, u32* wsum) {
    u32 x = s;
    #pragma unroll
    for (int d = 1; d < 64; d <<= 1) {
        u32 y = __shfl_up(x, (unsigned)d, 64);
        if (lane >= d) x += y;
    }
    if (lane == 63) wsum[wid] = x;
    __syncthreads();
    if (wid == 0) {
        u32 w = (lane < 16) ? wsum[lane] : 0u;
        #pragma unroll
        for (int d = 1; d < 16; d <<= 1) {
            u32 y = __shfl_up(w, (unsigned)d, 64);
            if (lane >= d) w += y;
        }
        if (lane < 16) wsum[lane] = w;
    }
    __syncthreads();
    return x + (wid ? wsum[wid - 1] : 0u);
}

// smallest bin with cumulative count >= thresh (guaranteed to exist)
__device__ __forceinline__ u32 find_cutoff(const u32* hist, u32 thresh, int tid,
                                           int wid, int lane, u32* wsum, u32* sB) {
    u32 h[16];
    const uint4* h4 = reinterpret_cast<const uint4*>(hist);
    #pragma unroll
    for (int k = 0; k < 4; ++k) {
        uint4 v = h4[tid * 4 + k];
        h[4 * k + 0] = v.x; h[4 * k + 1] = v.y; h[4 * k + 2] = v.z; h[4 * k + 3] = v.w;
    }
    u32 s = 0;
    #pragma unroll
    for (int b = 0; b < 16; ++b) s += h[b];
    u32 incl = block_scan(s, wid, lane, wsum);
    u32 before = incl - s;
    if (before < thresh && incl >= thresh) {
        u32 run = before;
        #pragma unroll
        for (int b = 0; b < 16; ++b) {
            run += h[b];
            if (run >= thresh) { sB[0] = (u32)(tid * 16 + b); break; }
        }
    }
    __syncthreads();
    u32 r = sB[0];
    __syncthreads();
    return r;
}

__global__ void __launch_bounds__(1024) k_mega(const float* __restrict__ cls,
                                               const float* __restrict__ loc,
                                               const float* __restrict__ anc,
                                               float4* __restrict__ out) {
    __shared__ u64 cand[CAP];              // 64KB: hist alias (A'/F), rankArr/flags alias (D)
    __shared__ __align__(16) u32 sfs[SCAP];
    __shared__ u32 sidx[SCAP];
    __shared__ float4 sbox[SCAP];          // 16KB (sorted boxes)
    __shared__ float  sarea[SCAP];
    __shared__ u64 smask[MROWS][MW];       // 18KB
    __shared__ float4 kept[OUTK];
    __shared__ float  karea[OUTK];
    __shared__ float4 cbox[64];
    __shared__ float  carea[64];
    __shared__ u64 supw[16];
    __shared__ u64 sbyp[1024];             // 8KB
    __shared__ u32 wsum[16];
    __shared__ u32 sB[2];
    __shared__ u32 shu[8];                 // 0:csRaw 1:totF 4:kc 5:i0 6:tie

    const int tid = threadIdx.x;
    const int wid = tid >> 6;
    const int lane = tid & 63;
    u32* hist = (u32*)cand;
    const uint4* cls4 = reinterpret_cast<const uint4*>(cls);

    // ---- A': zero hist; sampled histogram (every 4th uint4) ----
    for (int i = tid; i < NBINS; i += 1024) hist[i] = 0;
    if (tid < 8) shu[tid] = 0;
    __syncthreads();
    {
        uint4 s0 = ld_cls4(cls4, 4 * tid);
        uint4 s1 = ld_cls4(cls4, 4 * (tid + 1024));
        uint4 s2 = ld_cls4(cls4, 4 * (tid + 2048));
        bool has3 = tid < (SAMP_U4 - 3072);
        uint4 s3 = has3 ? ld_cls4(cls4, 4 * (tid + 3072)) : make_uint4(0u,0u,0u,0u);
        atomicAdd(&hist[flipu(s0.x) >> 18], 1u); atomicAdd(&hist[flipu(s0.y) >> 18], 1u);
        atomicAdd(&hist[flipu(s0.z) >> 18], 1u); atomicAdd(&hist[flipu(s0.w) >> 18], 1u);
        atomicAdd(&hist[flipu(s1.x) >> 18], 1u); atomicAdd(&hist[flipu(s1.y) >> 18], 1u);
        atomicAdd(&hist[flipu(s1.z) >> 18], 1u); atomicAdd(&hist[flipu(s1.w) >> 18], 1u);
        atomicAdd(&hist[flipu(s2.x) >> 18], 1u); atomicAdd(&hist[flipu(s2.y) >> 18], 1u);
        atomicAdd(&hist[flipu(s2.z) >> 18], 1u); atomicAdd(&hist[flipu(s2.w) >> 18], 1u);
        if (has3) {
            atomicAdd(&hist[flipu(s3.x) >> 18], 1u); atomicAdd(&hist[flipu(s3.y) >> 18], 1u);
            atomicAdd(&hist[flipu(s3.z) >> 18], 1u); atomicAdd(&hist[flipu(s3.w) >> 18], 1u);
        }
    }
    __syncthreads();
    const u32 B1 = find_cutoff(hist, SRANK, tid, wid, lane, wsum, sB);

    // ---- C: count pass (registers) -> scan -> write pass ----
    u64 bm = 0;
    u32 cnt = 0;
    #pragma unroll
    for (int half = 0; half < 2; ++half) {
        uint4 buf[7];
        #pragma unroll
        for (int kk = 0; kk < 7; ++kk) {
            int i = (half * 7 + kk) * 1024 + tid;
            buf[kk] = (i < TOT_U4) ? ld_cls4(cls4, i) : make_uint4(0xFFFFFFFFu,0xFFFFFFFFu,0xFFFFFFFFu,0xFFFFFFFFu);
        }
        #pragma unroll
        for (int kk = 0; kk < 7; ++kk) {
            int i = (half * 7 + kk) * 1024 + tid;
            if (i < TOT_U4) {
                #pragma unroll
                for (int c = 0; c < 4; ++c) {
                    u32 b = (c == 0) ? buf[kk].x : (c == 1) ? buf[kk].y
                          : (c == 2) ? buf[kk].z : buf[kk].w;
                    if ((flipu(b) >> 18) <= B1) {
                        cnt++;
                        bm |= 1ull << ((half * 7 + kk) * 4 + c);
                    }
                }
            }
        }
    }
    u32 incl = block_scan(cnt, wid, lane, wsum);
    u32 base = incl - cnt;
    if (tid == 1023) shu[0] = incl;     // total csRaw
    // zero rankArr/flags (hist dead) + smask while scan settles
    ((u32*)cand)[tid] = 0u;             // rankArr
    ((u32*)cand)[1024 + tid] = 0u;      // flags
    for (int i = tid; i < MROWS * MW; i += 1024) ((u64*)smask)[i] = 0ull;
    __syncthreads();
    const u32 csRaw = shu[0];
    const u32 cs = csRaw < SCAP ? csRaw : SCAP;
    const bool fast = (csRaw <= SCAP);

    if (fast) {
        u64 m = bm;
        u32 o = base;
        while (m) {
            int b = __ffsll((unsigned long long)m) - 1;
            m &= m - 1;
            int kk = b >> 2, c = b & 3;
            int i = kk * 1024 + tid;
            uint4 v = ld_cls4(cls4, i);
            u32 raw = (c == 0) ? v.x : (c == 1) ? v.y : (c == 2) ? v.z : v.w;
            int ch = i / CH_U4;
            int e4 = i - ch * CH_U4;
            u32 n = (u32)((e4 * 4 + c) * ADIM + ch);
            if (o < SCAP) { sfs[o] = flipu(raw); sidx[o] = n; }
            o++;
        }
    }
    if (tid >= (int)cs) { sfs[tid] = 0xFFFFFFFFu; sidx[tid] = 0xFFFFFFFFu; }
    __syncthreads();

    // ---- D: distributed counting-rank + scatter/decode ----
    if (fast) {
        u32* rankArr = (u32*)cand;
        u32* flags = ((u32*)cand) + 1024;
        {
            const int g = tid & 255;       // candidate group: g, g+256, g+512, g+768
            const int q = tid >> 8;        // j-quarter
            u32 f0 = sfs[g], f1 = sfs[g + 256], f2 = sfs[g + 512], f3 = sfs[g + 768];
            u32 r0 = 0, r1 = 0, r2 = 0, r3 = 0;
            const u32 nj4 = (cs + 3u) >> 2;
            const u32 lo4 = (nj4 * (u32)q) >> 2;
            const u32 hi4 = (nj4 * (u32)(q + 1)) >> 2;
            const uint4* sf4 = reinterpret_cast<const uint4*>(sfs);
            for (u32 j4 = lo4; j4 < hi4; ++j4) {
                uint4 v = sf4[j4];
                r0 += (v.x < f0) + (v.y < f0) + (v.z < f0) + (v.w < f0);
                r1 += (v.x < f1) + (v.y < f1) + (v.z < f1) + (v.w < f1);
                r2 += (v.x < f2) + (v.y < f2) + (v.z < f2) + (v.w < f2);
                r3 += (v.x < f3) + (v.y < f3) + (v.z < f3) + (v.w < f3);
            }
            if ((u32)g < cs && r0) atomicAdd(&rankArr[g], r0);
            if ((u32)(g + 256) < cs && r1) atomicAdd(&rankArr[g + 256], r1);
            if ((u32)(g + 512) < cs && r2) atomicAdd(&rankArr[g + 512], r2);
            if ((u32)(g + 768) < cs && r3) atomicAdd(&rankArr[g + 768], r3);
        }
        __syncthreads();
        if ((u32)tid < cs) {
            u32 rk = rankArr[tid];
            if (rk < SCAP) {
                u32 old = atomicExch(&flags[rk], 1u);
                if (old) shu[6] = 1u;      // fs tie -> exact re-rank below
                float4 b = decode_box(loc, anc, sidx[tid]);
                sbox[rk] = b;
                sarea[rk] = (b.z - b.x) * (b.w - b.y);
            } else shu[6] = 1u;
        }
        __syncthreads();
        if (shu[6]) {                      // exact (fs,idx) re-rank (rare: fs ties)
            if ((u32)tid < cs) {
                u32 myf = sfs[tid], myi = sidx[tid];
                u32 rk = 0;
                for (u32 j = 0; j < cs; ++j) {
                    u32 f = sfs[j];
                    rk += (f < myf) || (f == myf && sidx[j] < myi);
                }
                float4 b = decode_box(loc, anc, myi);
                sbox[rk] = b;
                sarea[rk] = (b.z - b.x) * (b.w - b.y);
            }
            __syncthreads();
        }

        // ---- E: wave-tiled suppression matrix ----
        const u32 rowsv = cs < MROWS ? cs : MROWS;
        for (int t = wid; t < NTILE; t += 16) {
            int rt = 0;
            while ((rt + 1) * (rt + 2) / 2 <= t) rt++;
            int jt = t - rt * (rt + 1) / 2;
            int row = rt * 64 + lane;
            bool rv = row < (int)rowsv;
            float4 rb = sbox[rv ? row : 0];
            float rba = sarea[rv ? row : 0];
            u64 msk = 0;
            #pragma unroll 4
            for (int jj = 0; jj < 64; ++jj) {
                int j = jt * 64 + jj;
                float4 bj = sbox[j];       // broadcast
                float baj = sarea[j];
                if (j < row && rv && iou_gt(rb, rba, bj, baj)) msk |= 1ull << jj;
            }
            if (rv) smask[row][jt] = msk;
        }
        __syncthreads();

        // greedy resolution on wave 0: bitmask ballot fixed point
        if (wid == 0) {
            u32 kc = 0, nexti0 = 0;
            u64 K[MW];
            #pragma unroll
            for (int w = 0; w < MW; ++w) K[w] = 0ull;
            #pragma unroll
            for (int cw = 0; cw < MW; ++cw) {
                u32 i0 = (u32)cw * 64u;
                if (i0 < rowsv && kc < OUTK) {
                    u32 ci = i0 + (u32)lane;
                    bool valid = ci < rowsv;
                    u64 myw[MW];
                    #pragma unroll
                    for (int w = 0; w < MW; ++w) myw[w] = valid ? smask[ci][w] : 0ull;
                    u64 supk = 0;
                    #pragma unroll
                    for (int w = 0; w < MW; ++w) supk |= myw[w] & K[w];
                    bool ia = valid && (supk == 0ull);
                    u64 inch = myw[cw] & ((1ull << lane) - 1ull);
                    u64 A = __ballot(ia ? 1 : 0);
                    for (int itx = 0; itx < 64; ++itx) {
                        bool na = ia && ((inch & A) == 0ull);
                        u64 A2 = __ballot(na ? 1 : 0);
                        if (A2 == A) break;
                        A = A2;
                    }
                    bool kp = (A >> lane) & 1;
                    u32 rank = (u32)__popcll(A & ((1ull << lane) - 1ull));
                    if (kp && kc + rank < OUTK) {
                        float4 c = sbox[ci];
                        kept[kc + rank] = c;
                        karea[kc + rank] = sarea[ci];
                        out[kc + rank] = c;
                    }
                    K[cw] = A;
                    kc += (u32)__popcll(A);
                    nexti0 = i0 + 64;
                }
            }
            if (lane == 0) {
                shu[4] = kc > OUTK ? OUTK : kc;
                shu[5] = nexti0;
            }
        }

        // chunked NMS over remainder [nexti0, cs)
        const u32 limit = cs;
        while (true) {
            __syncthreads();
            u32 kc = shu[4], i0 = shu[5];
            if (kc >= OUTK || i0 >= limit) break;
            u32 ci = i0 + (u32)lane;
            bool valid = ci < limit;
            float4 c = sbox[valid ? ci : 0];
            float ca = sarea[valid ? ci : 0];

            bool sup = false;
            for (u32 j = (u32)wid; j < kc; j += 16)
                sup = sup || iou_gt(c, ca, kept[j], karea[j]);
            u64 bal = __ballot(sup ? 1 : 0);
            if (lane == 0) supw[wid] = bal;

            u64 sby = 0;
            u32 smax = 4u * wid + 4u; if (smax > 63u) smax = 63u;
            for (u32 s = 4u * wid + 1u; s <= smax; ++s) {
                u32 p = ((u32)lane + s) & 63u;
                if (p < (u32)lane && (i0 + p) < limit)
                    if (iou_gt(c, ca, sbox[i0 + p], sarea[i0 + p])) sby |= (1ull << p);
            }
            sbyp[wid * 64 + lane] = sby;
            __syncthreads();

            if (wid == 0) {
                u64 sup64 = 0, sbyfull = 0;
                #pragma unroll
                for (int w = 0; w < 16; ++w) { sup64 |= supw[w]; sbyfull |= sbyp[w * 64 + lane]; }
                bool ia = valid && !((sup64 >> lane) & 1);
                u64 A = __ballot(ia ? 1 : 0);
                for (int itx = 0; itx < 64; ++itx) {
                    bool na = ia && ((sbyfull & A) == 0);
                    u64 A2 = __ballot(na ? 1 : 0);
                    if (A2 == A) break;
                    A = A2;
                }
                bool kp = (A >> lane) & 1;
                u32 rank = (u32)__popcll(A & ((1ull << lane) - 1ull));
                if (kp && kc + rank < OUTK) {
                    kept[kc + rank] = c; karea[kc + rank] = ca; out[kc + rank] = c;
                }
                if (lane == 0) {
                    u32 nk = kc + (u32)__popcll(A);
                    shu[4] = nk > OUTK ? OUTK : nk;
                    shu[5] = i0 + 64;
                }
            }
        }
    }

    // ---- Fallback: exact hist -> B2 -> compact -> bitonic 8192 -> NMS ----
    __syncthreads();
    if (shu[4] < OUTK) {
        const u32 consumed = fast ? cs : 0u;
        // F1: zero hist
        for (int i = tid; i < NBINS; i += 1024) hist[i] = 0;
        __syncthreads();
        // F2: exact full histogram
        #pragma unroll
        for (int half = 0; half < 2; ++half) {
            uint4 buf[7];
            #pragma unroll
            for (int kk = 0; kk < 7; ++kk) {
                int i = (half * 7 + kk) * 1024 + tid;
                buf[kk] = (i < TOT_U4) ? ld_cls4(cls4, i) : make_uint4(0u,0u,0u,0u);
            }
            #pragma unroll
            for (int kk = 0; kk < 7; ++kk) {
                int i = (half * 7 + kk) * 1024 + tid;
                if (i < TOT_U4) {
                    atomicAdd(&hist[flipu(buf[kk].x) >> 18], 1u);
                    atomicAdd(&hist[flipu(buf[kk].y) >> 18], 1u);
                    atomicAdd(&hist[flipu(buf[kk].z) >> 18], 1u);
                    atomicAdd(&hist[flipu(buf[kk].w) >> 18], 1u);
                }
            }
        }
        __syncthreads();
        // F3: exact B2 (rank-6000 bin)
        const u32 B2 = find_cutoff(hist, TOPK, tid, wid, lane, wsum, sB);
        // F4: count + scan + write keys into cand (hist dead)
        u64 bm2 = 0;
        u32 cnt2 = 0;
        #pragma unroll
        for (int half = 0; half < 2; ++half) {
            uint4 buf[7];
            #pragma unroll
            for (int kk = 0; kk < 7; ++kk) {
                int i = (half * 7 + kk) * 1024 + tid;
                buf[kk] = (i < TOT_U4) ? ld_cls4(cls4, i) : make_uint4(0xFFFFFFFFu,0xFFFFFFFFu,0xFFFFFFFFu,0xFFFFFFFFu);
            }
            #pragma unroll
            for (int kk = 0; kk < 7; ++kk) {
                int i = (half * 7 + kk) * 1024 + tid;
                if (i < TOT_U4) {
                    #pragma unroll
                    for (int c = 0; c < 4; ++c) {
                        u32 b = (c == 0) ? buf[kk].x : (c == 1) ? buf[kk].y
                              : (c == 2) ? buf[kk].z : buf[kk].w;
                        if ((flipu(b) >> 18) <= B2) {
                            cnt2++;
                            bm2 |= 1ull << ((half * 7 + kk) * 4 + c);
                        }
                    }
                }
            }
        }
        __syncthreads();          // hist reads in find_cutoff complete before overwrite
        for (int i = tid; i < CAP; i += 1024) cand[i] = ~0ull;
        u32 incl2 = block_scan(cnt2, wid, lane, wsum);
        u32 base2 = incl2 - cnt2;
        if (tid == 1023) shu[1] = incl2;
        __syncthreads();
        {
            u64 m = bm2;
            u32 o = base2;
            while (m) {
                int b = __ffsll((unsigned long long)m) - 1;
                m &= m - 1;
                int kk = b >> 2, c = b & 3;
                int i = kk * 1024 + tid;
                uint4 v = ld_cls4(cls4, i);
                u32 raw = (c == 0) ? v.x : (c == 1) ? v.y : (c == 2) ? v.z : v.w;
                int ch = i / CH_U4;
                int e4 = i - ch * CH_U4;
                u32 n = (u32)((e4 * 4 + c) * ADIM + ch);
                if (o < CAP) cand[o] = ((u64)flipu(raw) << 32) | n;
                o++;
            }
        }
        __syncthreads();
        const u32 totF = shu[1];
        const u32 limfb = totF < TOPK ? totF : TOPK;
        // F5: bitonic sort 8192
        for (int seg = wid; seg < CAP / 64; seg += 16) {
            u64 v = cand[seg * 64 + lane];
            #pragma unroll
            for (int k = 2; k <= 64; k <<= 1)
                #pragma unroll
                for (int j = k >> 1; j >= 1; j >>= 1)
                    v = ce64(v, j, lane, (((seg * 64 + lane) & k) == 0));
            cand[seg * 64 + lane] = v;
        }
        __syncthreads();
        for (int k = 128; k <= CAP; k <<= 1) {
            for (int j = k >> 1; j >= 64; j >>= 1) {
                for (u32 p = (u32)tid; p < CAP / 2; p += 1024) {
                    u32 i = ((p & ~(u32)(j - 1)) << 1) | (p & (u32)(j - 1));
                    u32 l = i | (u32)j;
                    bool up = ((i & (u32)k) == 0);
                    u64 a = cand[i], b = cand[l];
                    if ((a > b) == up) { cand[i] = b; cand[l] = a; }
                }
                __syncthreads();
            }
            for (int seg = wid; seg < CAP / 64; seg += 16) {
                u64 v = cand[seg * 64 + lane];
                bool up = (((seg * 64) & k) == 0);
                #pragma unroll
                for (int j = 32; j >= 1; j >>= 1) v = ce64(v, j, lane, up);
                cand[seg * 64 + lane] = v;
            }
            __syncthreads();
        }
        // F6: chunked NMS from consumed
        if (tid == 0) shu[5] = consumed;
        while (true) {
            __syncthreads();
            u32 kc = shu[4], i0 = shu[5];
            if (kc >= OUTK || i0 >= limfb) break;
            if (wid == 0) {
                u32 ci = i0 + (u32)lane;
                u32 n = (ci < limfb) ? (u32)cand[ci] : 0u;
                float4 b = decode_box(loc, anc, n);
                cbox[lane] = b;
                carea[lane] = (b.z - b.x) * (b.w - b.y);
            }
            __syncthreads();
            u32 ci = i0 + (u32)lane;
            bool valid = ci < limfb;
            float4 c = cbox[lane];
            float ca = carea[lane];
            bool sup = false;
            for (u32 j = (u32)wid; j < kc; j += 16)
                sup = sup || iou_gt(c, ca, kept[j], karea[j]);
            u64 bal = __ballot(sup ? 1 : 0);
            if (lane == 0) supw[wid] = bal;
            u64 sby = 0;
            u32 smax = 4u * wid + 4u; if (smax > 63u) smax = 63u;
            for (u32 s = 4u * wid + 1u; s <= smax; ++s) {
                u32 p = ((u32)lane + s) & 63u;
                if (p < (u32)lane && (i0 + p) < limfb)
                    if (iou_gt(c, ca, cbox[p], carea[p])) sby |= (1ull << p);
            }
            sbyp[wid * 64 + lane] = sby;
            __syncthreads();
            if (wid == 0) {
                u64 sup64 = 0, sbyfull = 0;
                #pragma unroll
                for (int w = 0; w < 16; ++w) { sup64 |= supw[w]; sbyfull |= sbyp[w * 64 + lane]; }
                bool ia = valid && !((sup64 >> lane) & 1);
                u64 A = __ballot(ia ? 1 : 0);
                for (int itx = 0; itx < 64; ++itx) {
                    bool na = ia && ((sbyfull & A) == 0);
                    u64 A2 = __ballot(na ? 1 : 0);
                    if (A2 == A) break;
                    A = A2;
                }
                bool kp = (A >> lane) & 1;
                u32 rank = (u32)__popcll(A & ((1ull << lane) - 1ull));
                if (kp && kc + rank < OUTK) {
                    kept[kc + rank] = c; karea[kc + rank] = ca; out[kc + rank] = c;
                }
                if (lane == 0) {
                    u32 nk = kc + (u32)__popcll(A);
                    shu[4] = nk > OUTK ? OUTK : nk;
                    shu[5] = i0 + 64;
                }
            }
        }
    }

    // ---- zero-pad ----
    __syncthreads();
    u32 kc = shu[4];
    for (u32 r = (u32)tid; r < OUTK; r += 1024)
        if (r >= kc) out[r] = make_float4(0.f, 0.f, 0.f, 0.f);
}

extern "C" void kernel_launch(void* const* d_in, const int* in_sizes, int n_in,
                              void* d_out, int out_size, void* d_ws, size_t ws_size,
                              hipStream_t stream) {
    const float* cls = (const float*)d_in[0];   // (1, 18, 64, 96)
    const float* loc = (const float*)d_in[1];   // (1, 36, 64, 96)
    const float* anc = (const float*)d_in[2];   // (55296, 4)
    k_mega<<<1, 1024, 0, stream>>>(cls, loc, anc, (float4*)d_out);
}